// Round 3
// baseline (760.748 us; speedup 1.0000x reference)
//
#include <hip/hip_runtime.h>

// Chamfer 2D via exact bucketed NN search. B=4, N=M=8192, D=2.
// Out layout (flat float32): dist1[32768] | dist2[32768] | idx1[32768] | idx2[32768]
//
// Algorithm:
//  1) bucketize_kernel (8 blocks, one per (set,b)): histogram points into 256
//     x-buckets (exact-float edges XLO + k*XW), prefix-sum, scatter into a
//     bucketed float4 array {x, y, orig_idx_as_float, 0}.
//  2) nn_scan_kernel: each query (in bucketed order, so neighboring lanes have
//     neighboring x -> low divergence) scans its own bucket then walks outward,
//     terminating a side when fl(dxe^2) > best (dxe = dist to bucket near edge).
//     Exact-conservative: d = fl(fl(dx^2)+fl(dy^2)) >= fl(dx^2) >= fl(dxe^2).
//     Tie-break (d == best -> smaller idx) matches np.argmin first-occurrence.
// Pair distance math identical to the validated R2 kernel (__fmul_rn/__fadd_rn).

#define BB 4
#define NPTS 8192
#define NBUK 256
#define XLO (-6.0f)
#define XW  (0.046875f)   // 12/256 = 3*2^-6, exact in fp32; edges XLO+k*XW exact

__device__ __forceinline__ int bucket_of(float x) {
    int k = (int)floorf((x - XLO) * (1.0f / XW));
    k = k < 0 ? 0 : (k > NBUK - 1 ? NBUK - 1 : k);
    // fixup against exact edges so invariants hold:
    //  k>0        -> x >= XLO + k*XW      (left edge)
    //  k<NBUK-1   -> x <  XLO + (k+1)*XW  (right edge)
#pragma unroll
    for (int it = 0; it < 2; ++it) {
        if (k < NBUK - 1 && x >= XLO + (float)(k + 1) * XW) k++;
        else if (k > 0 && x < XLO + (float)k * XW) k--;
    }
    return k;
}

// One block per (set,b): sb = set*4 + b, set0=in1, set1=in2.
__global__ __launch_bounds__(512) void bucketize_kernel(
    const float* __restrict__ in1, const float* __restrict__ in2,
    float4* __restrict__ bpts, int* __restrict__ starts)
{
    const int sb = blockIdx.x;                 // 0..7
    const float* __restrict__ src = ((sb >= 4) ? in2 : in1) + (size_t)(sb & 3) * NPTS * 2;
    const int t = threadIdx.x;

    __shared__ int hist[NBUK];
    __shared__ int cur[NBUK];
    __shared__ int sA[NBUK], sB[NBUK];

    if (t < NBUK) hist[t] = 0;
    __syncthreads();

    for (int p = t; p < NPTS; p += 512) {
        const float x = src[2 * p];
        atomicAdd(&hist[bucket_of(x)], 1);
    }
    __syncthreads();

    // exclusive prefix sum over hist[256] (Hillis-Steele, double-buffered)
    if (t < NBUK) sA[t] = hist[t];
    __syncthreads();
    int* pa = sA; int* pb = sB;
    for (int off = 1; off < NBUK; off <<= 1) {
        if (t < NBUK) pb[t] = pa[t] + ((t >= off) ? pa[t - off] : 0);
        __syncthreads();
        int* tmp = pa; pa = pb; pb = tmp;
    }
    int excl = 0;
    if (t < NBUK) {
        excl = (t == 0) ? 0 : pa[t - 1];
        cur[t] = excl;
        starts[sb * (NBUK + 1) + t] = excl;
    }
    if (t == 0) starts[sb * (NBUK + 1) + NBUK] = NPTS;
    __syncthreads();

    // scatter: bucket-internal order is race-dependent but the final argmin is
    // order-independent (explicit (d, idx) tie-break at query time).
    for (int p = t; p < NPTS; p += 512) {
        const float x = src[2 * p];
        const float y = src[2 * p + 1];
        const int k = bucket_of(x);
        const int pos = atomicAdd(&cur[k], 1);
        bpts[(size_t)sb * NPTS + pos] = make_float4(x, y, (float)p, 0.0f);
    }
}

// 256 blocks x 256 threads: (dir, b, 256-query chunk); queries in bucketed order.
__global__ __launch_bounds__(256) void nn_scan_kernel(
    const float4* __restrict__ bpts, const int* __restrict__ starts,
    float* __restrict__ out)
{
    const int bid   = blockIdx.x;
    const int chunk = bid & 31;
    const int db    = bid >> 5;          // dir*4 + b
    const int dir   = db >> 2;
    const int b     = db & 3;
    const int qsb   = (dir ? 4 : 0) + b; // dir0: queries=set1, refs=set2
    const int rsb   = (dir ? 0 : 4) + b;

    const float4* __restrict__ Q  = bpts + (size_t)qsb * NPTS;
    const float4* __restrict__ Rf = bpts + (size_t)rsb * NPTS;
    const int* __restrict__ rst   = starts + rsb * (NBUK + 1);

    const int t = chunk * 256 + threadIdx.x;     // bucketed query position
    const float4 q = Q[t];
    const float qx = q.x, qy = q.y;
    const int qid = (int)q.z;

    float best = 1e30f;
    float bif  = 0.0f;    // best index as float (exact for idx < 2^24)

    const int cb = bucket_of(qx);

    auto scan = [&](int k) {
        const int e = rst[k + 1];
        for (int p = rst[k]; p < e; ++p) {
            const float4 r = Rf[p];
            const float dx = qx - r.x;
            const float dy = qy - r.y;
            // identical rounding to reference: (dx*dx)+(dy*dy), no FMA
            const float d = __fadd_rn(__fmul_rn(dx, dx), __fmul_rn(dy, dy));
            const bool c = (d < best) || (d == best && r.z < bif);
            best = c ? d : best;
            bif  = c ? r.z : bif;
        }
    };

    scan(cb);

    int L = cb - 1, Rb = cb + 1;
    bool goL = (L >= 0);
    bool goR = (Rb <= NBUK - 1);
    while (goL || goR) {
        if (goL) {
            // points in bucket L have x <= right_edge(L) (assignment invariant),
            // and qx >= left_edge(cb) = right_edge(cb-1) >= right_edge(L)
            const float dxe = qx - (XLO + (float)(L + 1) * XW);   // >= 0
            if (__fmul_rn(dxe, dxe) > best) {
                goL = false;                 // all further-left points: d > best
            } else {
                scan(L);
                --L; goL = (L >= 0);
            }
        }
        if (goR) {
            const float dxe = (XLO + (float)Rb * XW) - qx;        // >= 0
            if (__fmul_rn(dxe, dxe) > best) {
                goR = false;
            } else {
                scan(Rb);
                ++Rb; goR = (Rb <= NBUK - 1);
            }
        }
    }

    const int od = b * 8192 + qid;
    if (dir == 0) {
        out[od]         = best;        // dist1
        out[65536 + od] = bif;         // idx1
    } else {
        out[32768 + od] = best;        // dist2
        out[98304 + od] = bif;         // idx2
    }
}

extern "C" void kernel_launch(void* const* d_in, const int* in_sizes, int n_in,
                              void* d_out, int out_size, void* d_ws, size_t ws_size,
                              hipStream_t stream) {
    const float* in1 = (const float*)d_in[0];
    const float* in2 = (const float*)d_in[1];
    float* out = (float*)d_out;
    (void)in_sizes; (void)n_in; (void)out_size; (void)ws_size;

    // ws layout: bpts 8*8192*16B = 1 MiB, then starts 8*257*4B
    float4* bpts = (float4*)d_ws;
    int* starts  = (int*)((char*)d_ws + (size_t)8 * NPTS * sizeof(float4));

    bucketize_kernel<<<8, 512, 0, stream>>>(in1, in2, bpts, starts);
    nn_scan_kernel<<<256, 256, 0, stream>>>(bpts, starts, out);
}

// Round 4
// 93.843 us; speedup vs baseline: 8.1066x; 8.1066x over previous
//
#include <hip/hip_runtime.h>

// Chamfer 2D, exact: bucket-sort by x (256 exact-float-edge buckets), then a
// FIXED 512-candidate rank-window scan per query (regular, unroll-8, R2-style
// schedule), an exact-conservative x-bound check, and a brute-force fallback
// for the rare queries the window can't certify. All pair math is the
// validated __fmul_rn/__fadd_rn formula; ties broken lex (d, orig_idx) ==
// np.argmin first-occurrence. Outputs are exact regardless of bucket-internal
// (atomic) ordering.
// Out layout (flat f32): dist1[32768] | dist2[32768] | idx1[32768] | idx2[32768]

#define NPTS 8192
#define NBUK 256
#define XLO (-6.0f)
#define XW  (0.046875f)   // 3*2^-6: all edges XLO + k*XW are exact floats
#define WIN 512
#define PAD 180

__device__ __forceinline__ int bucket_of(float x) {
    int k = (int)floorf((x - XLO) * (1.0f / XW));
    k = k < 0 ? 0 : (k > NBUK - 1 ? NBUK - 1 : k);
    // enforce: k>0 -> x >= XLO+k*XW ; k<255 -> x < XLO+(k+1)*XW
#pragma unroll
    for (int it = 0; it < 2; ++it) {
        if (k < NBUK - 1 && x >= XLO + (float)(k + 1) * XW) k++;
        else if (k > 0 && x < XLO + (float)k * XW) k--;
    }
    return k;
}

// ---- 1) bucketize: 8 blocks (one per set*4+b), 1024 threads ---------------
__global__ __launch_bounds__(1024) void bucketize_kernel(
    const float* __restrict__ in1, const float* __restrict__ in2,
    float4* __restrict__ bpts, int* __restrict__ starts, int* __restrict__ cnt)
{
    const int sb = blockIdx.x;                 // 0..7
    const float* __restrict__ src = ((sb >= 4) ? in2 : in1) + (size_t)(sb & 3) * NPTS * 2;
    const int t = threadIdx.x;

    __shared__ int h4[NBUK][4];   // 4-way split histogram (copy = t&3)
    __shared__ int c4[NBUK][4];   // 4-way split scatter cursors
    __shared__ int sA[NBUK], sB[NBUK];

    for (int i = t; i < NBUK * 4; i += 1024) ((int*)h4)[i] = 0;
    if (sb == 0 && t == 0) *cnt = 0;           // fallback-queue counter
    __syncthreads();

    const int cp = t & 3;
    for (int p = t; p < NPTS; p += 1024)
        atomicAdd(&h4[bucket_of(src[2 * p])][cp], 1);
    __syncthreads();

    if (t < NBUK) sA[t] = h4[t][0] + h4[t][1] + h4[t][2] + h4[t][3];
    __syncthreads();
    int* pa = sA; int* pb = sB;
    for (int off = 1; off < NBUK; off <<= 1) {
        if (t < NBUK) pb[t] = pa[t] + ((t >= off) ? pa[t - off] : 0);
        __syncthreads();
        int* tmp = pa; pa = pb; pb = tmp;
    }
    if (t < NBUK) {
        int base = (t == 0) ? 0 : pa[t - 1];   // exclusive prefix
        starts[sb * (NBUK + 1) + t] = base;
        c4[t][0] = base; base += h4[t][0];
        c4[t][1] = base; base += h4[t][1];
        c4[t][2] = base; base += h4[t][2];
        c4[t][3] = base;
    }
    if (t == 0) starts[sb * (NBUK + 1) + NBUK] = NPTS;
    __syncthreads();

    for (int p = t; p < NPTS; p += 1024) {
        const float x = src[2 * p];
        const float y = src[2 * p + 1];
        const int k = bucket_of(x);
        const int pos = atomicAdd(&c4[k][cp], 1);
        bpts[(size_t)sb * NPTS + pos] = make_float4(x, y, (float)p, 0.0f);
    }
}

// ---- 2) window scan: 4 lanes/query, fixed 512-candidate window ------------
// grid = 2*4*8192*4 threads / 256 = 1024 blocks (4 waves/SIMD)
__global__ __launch_bounds__(256) void window_scan_kernel(
    const float4* __restrict__ bpts, const int* __restrict__ starts,
    float* __restrict__ out, int* __restrict__ cnt, int* __restrict__ queue)
{
    const int gtid  = blockIdx.x * 256 + threadIdx.x;
    const int sub   = gtid & 3;
    const int qslot = gtid >> 2;          // [0, 65536)
    const int qpos  = qslot & 8191;       // bucketed query position
    const int db    = qslot >> 13;        // dir*4 + b
    const int dir   = db >> 2;
    const int b     = db & 3;
    const int qsb   = (dir ? 4 : 0) + b;
    const int rsb   = (dir ? 0 : 4) + b;

    const float4* __restrict__ Q  = bpts + (size_t)qsb * NPTS;
    const float4* __restrict__ Rf = bpts + (size_t)rsb * NPTS;
    const int* __restrict__ rst   = starts + rsb * (NBUK + 1);

    const float4 q = Q[qpos];
    const float qx = q.x, qy = q.y;

    const int cb = bucket_of(qx);
    int wl = rst[cb] - PAD;
    wl = wl < 0 ? 0 : (wl > NPTS - WIN ? NPTS - WIN : wl);

    // 2 lex-min chains over this lane's 128 candidates (p = wl + sub + 4*i)
    float bd0 = 1e30f, bd1 = 1e30f, bz0 = 0.0f, bz1 = 0.0f;
    for (int i = 0; i < WIN / 4; i += 8) {
#pragma unroll
        for (int u = 0; u < 8; ++u) {
            const float4 r = Rf[wl + sub + 4 * (i + u)];
            const float dx = qx - r.x;
            const float dy = qy - r.y;
            // identical rounding to reference: (dx*dx)+(dy*dy), no FMA
            const float d = __fadd_rn(__fmul_rn(dx, dx), __fmul_rn(dy, dy));
            if (u & 1) {
                const bool c = (d < bd1) || (d == bd1 && r.z < bz1);
                bd1 = c ? d : bd1; bz1 = c ? r.z : bz1;
            } else {
                const bool c = (d < bd0) || (d == bd0 && r.z < bz0);
                bd0 = c ? d : bd0; bz0 = c ? r.z : bz0;
            }
        }
    }
    const bool cm = (bd1 < bd0) || (bd1 == bd0 && bz1 < bz0);
    float best = cm ? bd1 : bd0;
    float bif  = cm ? bz1 : bz0;

    // combine across the 4 sub-lanes of this query (lex (d, idx) min)
#pragma unroll
    for (int m = 1; m <= 2; m <<= 1) {
        const float od = __shfl_xor(best, m, 64);
        const float oz = __shfl_xor(bif,  m, 64);
        const bool c = (od < best) || (od == best && oz < bif);
        best = c ? od : best;
        bif  = c ? oz : bif;
    }

    if (sub == 0) {
        // exact-conservative certification:
        //  left : all p < wl have x <= right_edge(bucket(x[wl-1]))
        //  right: all p >= wl+WIN have x >= left_edge(bucket(x[wl+WIN]))
        //  d >= fl(dx^2) >= fl(dxe^2) > best  => cannot beat or tie best
        const int wr = wl + WIN;
        bool okL = (wl == 0), okR = (wr >= NPTS);
        if (!okL) {
            const float xl = Rf[wl - 1].x;
            const int kl = bucket_of(xl);
            if (kl < NBUK - 1) {                 // k=255 bucket: unbounded above
                const float dxe = qx - (XLO + (float)(kl + 1) * XW);
                okL = (dxe > 0.0f) && (__fmul_rn(dxe, dxe) > best);
            }
        }
        if (!okR) {
            const float xr = Rf[wr].x;
            const int kr = bucket_of(xr);
            if (kr > 0) {                        // k=0 bucket: unbounded below
                const float dxe = (XLO + (float)kr * XW) - qx;
                okR = (dxe > 0.0f) && (__fmul_rn(dxe, dxe) > best);
            }
        }

        const int qid = (int)q.z;
        const int od  = b * 8192 + qid;
        if (dir == 0) { out[od]         = best; out[65536 + od] = bif; }
        else          { out[32768 + od] = best; out[98304 + od] = bif; }

        if (!(okL && okR)) {
            const int pos = atomicAdd(cnt, 1);
            queue[pos] = qslot;                  // db*8192 + qpos
        }
    }
}

// ---- 3) fallback: one block cooperatively brute-forces one failed query ---
__global__ __launch_bounds__(256) void fallback_kernel(
    const float* __restrict__ in1, const float* __restrict__ in2,
    const float4* __restrict__ bpts, const int* __restrict__ cnt,
    const int* __restrict__ queue, float* __restrict__ out)
{
    __shared__ float sd[4], sz[4];
    const int n = *cnt;
    const int t = threadIdx.x;

    for (int item = blockIdx.x; item < n; item += gridDim.x) {
        const int qslot = queue[item];
        const int qpos  = qslot & 8191;
        const int db    = qslot >> 13;
        const int dir   = db >> 2;
        const int b     = db & 3;
        const int qsb   = (dir ? 4 : 0) + b;
        const float4 q  = bpts[(size_t)qsb * NPTS + qpos];
        const float qx = q.x, qy = q.y;
        // refs in ORIGINAL index order -> strict < keeps first occurrence
        const float2* __restrict__ P =
            (const float2*)((dir ? in1 : in2) + (size_t)b * NPTS * 2);

        float bd = 1e30f, bz = 0.0f;
        for (int j = t; j < NPTS; j += 256) {
            const float2 rp = P[j];
            const float dx = qx - rp.x;
            const float dy = qy - rp.y;
            const float d = __fadd_rn(__fmul_rn(dx, dx), __fmul_rn(dy, dy));
            const bool c = d < bd;               // per-thread: idx order
            bd = c ? d : bd;
            bz = c ? (float)j : bz;
        }
        // wave reduce (lex (d, idx))
#pragma unroll
        for (int m = 1; m < 64; m <<= 1) {
            const float od = __shfl_xor(bd, m, 64);
            const float oz = __shfl_xor(bz, m, 64);
            const bool c = (od < bd) || (od == bd && oz < bz);
            bd = c ? od : bd;
            bz = c ? oz : bz;
        }
        if ((t & 63) == 0) { sd[t >> 6] = bd; sz[t >> 6] = bz; }
        __syncthreads();
        if (t == 0) {
            float fbd = sd[0], fbz = sz[0];
#pragma unroll
            for (int w = 1; w < 4; ++w) {
                const bool c = (sd[w] < fbd) || (sd[w] == fbd && sz[w] < fbz);
                fbd = c ? sd[w] : fbd;
                fbz = c ? sz[w] : fbz;
            }
            const int qid = (int)q.z;
            const int od  = b * 8192 + qid;
            if (dir == 0) { out[od]         = fbd; out[65536 + od] = fbz; }
            else          { out[32768 + od] = fbd; out[98304 + od] = fbz; }
        }
        __syncthreads();   // protect sd/sz before next item
    }
}

extern "C" void kernel_launch(void* const* d_in, const int* in_sizes, int n_in,
                              void* d_out, int out_size, void* d_ws, size_t ws_size,
                              hipStream_t stream) {
    const float* in1 = (const float*)d_in[0];
    const float* in2 = (const float*)d_in[1];
    float* out = (float*)d_out;
    (void)in_sizes; (void)n_in; (void)out_size; (void)ws_size;

    // ws layout: bpts 8*8192*16B = 1 MiB | starts 8*257*4B | cnt 4B | queue 64K*4B
    char* w = (char*)d_ws;
    float4* bpts = (float4*)w;
    int* starts  = (int*)(w + (size_t)8 * NPTS * sizeof(float4));
    int* cnt     = starts + 8 * (NBUK + 1);
    int* queue   = cnt + 1;

    bucketize_kernel<<<8, 1024, 0, stream>>>(in1, in2, bpts, starts, cnt);
    window_scan_kernel<<<(2 * 4 * NPTS * 4) / 256, 256, 0, stream>>>(
        bpts, starts, out, cnt, queue);
    fallback_kernel<<<256, 256, 0, stream>>>(in1, in2, bpts, cnt, queue, out);
}

// Round 5
// 57.556 us; speedup vs baseline: 13.2175x; 1.6305x over previous
//
#include <hip/hip_runtime.h>

// Chamfer 2D exact NN, B=4, N=M=8192.
// Out (flat f32): dist1[32768] | dist2[32768] | idx1[32768] | idx2[32768]
//
// R5 structure:
//  1) bucketize (8 blocks): counting-sort both sets into 2048 x-buckets
//     (exact-float edges XLO + k*XW, XW = 3*2^-9). Records: float4(x,y,idx,0).
//  2) window_scan (1024 blocks, 64 queries + 4 waves each): qpos-centered
//     512-candidate rank window, staged in LDS (576 float4 = 9.2KB union).
//     Wave s scans candidate chunk [128s,128s+128) for all 64 queries with
//     lane=query -> contiguous conflict-free ds_read_b128. Lex (d,idx) min,
//     exact-conservative bucket-edge certification; failures -> queue.
//  3) fallback (2048 waves): one wave brute-forces one failed query over the
//     original (idx-ordered) array. Exact same pair math everywhere.

#define NPTS 8192
#define NBUK 2048
#define XLO  (-6.0f)
#define XW   (0.005859375f)   // 12/2048 = 3*2^-9, exact; all edges exact floats
#define WIN  512
#define UNI  (WIN + 64)       // staged union per 64-query block

__device__ __forceinline__ int bucket_of(float x) {
    int k = (int)floorf((x - XLO) * (1.0f / XW));
    k = k < 0 ? 0 : (k > NBUK - 1 ? NBUK - 1 : k);
    // enforce: k>0 -> x >= XLO+k*XW ; k<NBUK-1 -> x < XLO+(k+1)*XW
#pragma unroll
    for (int it = 0; it < 3; ++it) {
        if (k < NBUK - 1 && x >= XLO + (float)(k + 1) * XW) k++;
        else if (k > 0 && x < XLO + (float)k * XW) k--;
    }
    return k;
}

// ---- 1) bucketize: 8 blocks (sb = set*4+b), 1024 threads ------------------
__global__ __launch_bounds__(1024) void bucketize_kernel(
    const float* __restrict__ in1, const float* __restrict__ in2,
    float4* __restrict__ bpts, int* __restrict__ cnt)
{
    __shared__ int h4[NBUK][4];   // 32KB split histogram
    __shared__ int c4[NBUK][4];   // 32KB scatter cursors
    __shared__ int tsA[1024], tsB[1024];

    const int sb = blockIdx.x;
    const float2* __restrict__ src =
        (const float2*)(((sb >= 4) ? in2 : in1) + (size_t)(sb & 3) * NPTS * 2);
    const int t = threadIdx.x;

    for (int i = t; i < NBUK * 4; i += 1024) ((int*)h4)[i] = 0;
    if (sb == 0 && t == 0) *cnt = 0;
    __syncthreads();

    const int cp = t & 3;
    for (int p = t; p < NPTS; p += 1024)
        atomicAdd(&h4[bucket_of(src[p].x)][cp], 1);
    __syncthreads();

    // two buckets per thread; scan pair-totals (Hillis-Steele, 10 rounds)
    const int ha = h4[2 * t][0] + h4[2 * t][1] + h4[2 * t][2] + h4[2 * t][3];
    const int hb = h4[2 * t + 1][0] + h4[2 * t + 1][1] + h4[2 * t + 1][2] + h4[2 * t + 1][3];
    tsA[t] = ha + hb;
    __syncthreads();
    int* pa = tsA; int* pb = tsB;
    for (int off = 1; off < 1024; off <<= 1) {
        pb[t] = pa[t] + ((t >= off) ? pa[t - off] : 0);
        __syncthreads();
        int* tmp = pa; pa = pb; pb = tmp;
    }
    int base = (t == 0) ? 0 : pa[t - 1];       // exclusive prefix of pair
    // bucket 2t cursors
    c4[2 * t][0] = base; base += h4[2 * t][0];
    c4[2 * t][1] = base; base += h4[2 * t][1];
    c4[2 * t][2] = base; base += h4[2 * t][2];
    c4[2 * t][3] = base; base += h4[2 * t][3];
    // bucket 2t+1 cursors
    c4[2 * t + 1][0] = base; base += h4[2 * t + 1][0];
    c4[2 * t + 1][1] = base; base += h4[2 * t + 1][1];
    c4[2 * t + 1][2] = base; base += h4[2 * t + 1][2];
    c4[2 * t + 1][3] = base;
    __syncthreads();

    // scatter (bucket-internal order nondeterministic; outputs stay exact via
    // explicit (d, idx) lex tie-break at query time)
    for (int p = t; p < NPTS; p += 1024) {
        const float2 xy = src[p];
        const int k = bucket_of(xy.x);
        const int pos = atomicAdd(&c4[k][cp], 1);
        bpts[(size_t)sb * NPTS + pos] = make_float4(xy.x, xy.y, (float)p, 0.0f);
    }
}

// ---- 2) window scan: 1024 blocks, 64 queries/block, LDS-staged ------------
__global__ __launch_bounds__(256) void window_scan_kernel(
    const float4* __restrict__ bpts, float* __restrict__ out,
    int* __restrict__ cnt, int* __restrict__ queue)
{
    __shared__ float4 win[UNI];          // 9216 B
    __shared__ float pbd[4][64];
    __shared__ float pbz[4][64];

    const int bid = blockIdx.x;
    const int t   = threadIdx.x;
    const int q0slot = bid * 64;         // first qslot of block
    const int db  = q0slot >> 13;        // dir*4 + b  (64 | 8192: no straddle)
    const int dir = db >> 2;
    const int b   = db & 3;
    const int q0  = q0slot & 8191;
    const int qsb = (dir ? 4 : 0) + b;
    const int rsb = (dir ? 0 : 4) + b;

    const float4* __restrict__ Q  = bpts + (size_t)qsb * NPTS;
    const float4* __restrict__ Rf = bpts + (size_t)rsb * NPTS;

    int u0 = q0 - WIN / 2;
    u0 = u0 < 0 ? 0 : (u0 > NPTS - UNI ? NPTS - UNI : u0);

    // stage union [u0, u0+576): coalesced float4 loads
    win[t]       = Rf[u0 + t];
    win[t + 256] = Rf[u0 + 256 + t];
    if (t < UNI - 512) win[t + 512] = Rf[u0 + 512 + t];
    __syncthreads();

    const int s = t >> 6;                // wave id = candidate chunk
    const int L = t & 63;                // lane = query-in-block
    const int qpos = q0 + L;
    const float4 q = Q[qpos];
    const float qx = q.x, qy = q.y;

    int wl = qpos - WIN / 2;
    wl = wl < 0 ? 0 : (wl > NPTS - WIN ? NPTS - WIN : wl);
    const int base = (wl - u0) + (s << 7);   // lane-contiguous -> conflict-free

    // two independent lex-min chains over this wave's 128-candidate chunk
    float bd0 = 1e30f, bd1 = 1e30f, bz0 = 0.0f, bz1 = 0.0f;
    for (int i = 0; i < 128; i += 8) {
#pragma unroll
        for (int u = 0; u < 8; ++u) {
            const float4 r = win[base + i + u];
            const float dx = qx - r.x;
            const float dy = qy - r.y;
            // identical rounding to reference: (dx*dx)+(dy*dy), no FMA
            const float d = __fadd_rn(__fmul_rn(dx, dx), __fmul_rn(dy, dy));
            if (u & 1) {
                const bool c = (d < bd1) || (d == bd1 && r.z < bz1);
                bd1 = c ? d : bd1; bz1 = c ? r.z : bz1;
            } else {
                const bool c = (d < bd0) || (d == bd0 && r.z < bz0);
                bd0 = c ? d : bd0; bz0 = c ? r.z : bz0;
            }
        }
    }
    const bool cm = (bd1 < bd0) || (bd1 == bd0 && bz1 < bz0);
    pbd[s][L] = cm ? bd1 : bd0;
    pbz[s][L] = cm ? bz1 : bz0;
    __syncthreads();

    if (t < 64) {                        // wave 0: combine, certify, write
        float best = pbd[0][L];
        float bif  = pbz[0][L];
#pragma unroll
        for (int k = 1; k < 4; ++k) {
            const float dv = pbd[k][L];
            const float zv = pbz[k][L];
            const bool c = (dv < best) || (dv == best && zv < bif);
            best = c ? dv : best;
            bif  = c ? zv : bif;
        }

        // exact-conservative certification:
        //  left : all p<wl have x <= right_edge(bucket(x[wl-1]))
        //  right: all p>=wl+WIN have x >= left_edge(bucket(x[wl+WIN]))
        //  outside d >= fl(dx^2) >= fl(dxe^2) > best => can't beat or tie
        const int wr = wl + WIN;
        bool okL = (wl == 0), okR = (wr >= NPTS);
        if (!okL) {
            const int kl = bucket_of(Rf[wl - 1].x);
            if (kl < NBUK - 1) {
                const float dxe = qx - (XLO + (float)(kl + 1) * XW);
                okL = (dxe > 0.0f) && (__fmul_rn(dxe, dxe) > best);
            }
        }
        if (!okR) {
            const int kr = bucket_of(Rf[wr].x);
            if (kr > 0) {
                const float dxe = (XLO + (float)kr * XW) - qx;
                okR = (dxe > 0.0f) && (__fmul_rn(dxe, dxe) > best);
            }
        }

        const int qid = (int)q.z;
        const int od  = b * 8192 + qid;
        if (dir == 0) { out[od]         = best; out[65536 + od] = bif; }
        else          { out[32768 + od] = best; out[98304 + od] = bif; }

        if (!(okL && okR)) {
            const int pos = atomicAdd(cnt, 1);
            queue[pos] = q0slot + L;     // db*8192 + qpos
        }
    }
}

// ---- 3) fallback: one wave per failed query (2048 waves) ------------------
__global__ __launch_bounds__(256) void fallback_kernel(
    const float* __restrict__ in1, const float* __restrict__ in2,
    const float4* __restrict__ bpts, const int* __restrict__ cnt,
    const int* __restrict__ queue, float* __restrict__ out)
{
    const int n    = *cnt;
    const int gw   = (blockIdx.x << 2) + (threadIdx.x >> 6);  // global wave id
    const int lane = threadIdx.x & 63;

    for (int item = gw; item < n; item += 2048) {
        const int qslot = queue[item];
        const int qpos  = qslot & 8191;
        const int db    = qslot >> 13;
        const int dir   = db >> 2;
        const int b     = db & 3;
        const int qsb   = (dir ? 4 : 0) + b;
        const float4 q  = bpts[(size_t)qsb * NPTS + qpos];
        const float qx = q.x, qy = q.y;
        // refs in ORIGINAL index order; per-lane j increases -> strict <
        // keeps the first occurrence within a lane
        const float2* __restrict__ P =
            (const float2*)((dir ? in1 : in2) + (size_t)b * NPTS * 2);

        float bd = 1e30f, bz = 0.0f;
#pragma unroll 4
        for (int j = lane; j < NPTS; j += 64) {
            const float2 rp = P[j];
            const float dx = qx - rp.x;
            const float dy = qy - rp.y;
            const float d = __fadd_rn(__fmul_rn(dx, dx), __fmul_rn(dy, dy));
            const bool c = d < bd;
            bd = c ? d : bd;
            bz = c ? (float)j : bz;
        }
        // cross-lane lex (d, idx) reduce
#pragma unroll
        for (int m = 1; m < 64; m <<= 1) {
            const float od = __shfl_xor(bd, m, 64);
            const float oz = __shfl_xor(bz, m, 64);
            const bool c = (od < bd) || (od == bd && oz < bz);
            bd = c ? od : bd;
            bz = c ? oz : bz;
        }
        if (lane == 0) {
            const int qid = (int)q.z;
            const int od  = b * 8192 + qid;
            if (dir == 0) { out[od]         = bd; out[65536 + od] = bz; }
            else          { out[32768 + od] = bd; out[98304 + od] = bz; }
        }
    }
}

extern "C" void kernel_launch(void* const* d_in, const int* in_sizes, int n_in,
                              void* d_out, int out_size, void* d_ws, size_t ws_size,
                              hipStream_t stream) {
    const float* in1 = (const float*)d_in[0];
    const float* in2 = (const float*)d_in[1];
    float* out = (float*)d_out;
    (void)in_sizes; (void)n_in; (void)out_size; (void)ws_size;

    // ws layout: bpts 8*8192*16B = 1 MiB | cnt 4B | queue 65536*4B
    char* w = (char*)d_ws;
    float4* bpts = (float4*)w;
    int* cnt     = (int*)(w + (size_t)8 * NPTS * sizeof(float4));
    int* queue   = cnt + 1;

    bucketize_kernel<<<8, 1024, 0, stream>>>(in1, in2, bpts, cnt);
    window_scan_kernel<<<1024, 256, 0, stream>>>(bpts, out, cnt, queue);
    fallback_kernel<<<512, 256, 0, stream>>>(in1, in2, bpts, cnt, queue, out);
}

// Round 6
// 52.667 us; speedup vs baseline: 14.4446x; 1.0928x over previous
//
#include <hip/hip_runtime.h>

// Chamfer 2D exact NN, B=4, N=M=8192.
// Out (flat f32): dist1[32768] | dist2[32768] | idx1[32768] | idx2[32768]
//
// R6: bucketize rebuilt — counting-sort fully inside LDS (128KB point array),
// so the only global writes are LINEAR coalesced float4 stores (R5 scattered
// 8192 random 16B stores per set, the suspected ~20-40us elephant). Prefix
// scan is now a 3-barrier wave-shuffle scan (was 20-barrier Hillis-Steele).
// NBUK 2048->1024 (XW = 3*2^-8, all edges exact floats; certification slack
// grows by <= one bucket width 0.006 vs 0.078 window half-radius).
// window_scan / fallback semantics unchanged from the absmax=0-validated R5.

#define NPTS 8192
#define NBUK 1024
#define XLO  (-6.0f)
#define XW   (0.01171875f)    // 12/1024 = 3*2^-8, exact; all edges exact floats
#define WIN  512
#define UNI  (WIN + 64)       // staged union per 64-query block

__device__ __forceinline__ int bucket_of(float x) {
    int k = (int)floorf((x - XLO) * (1.0f / XW));
    k = k < 0 ? 0 : (k > NBUK - 1 ? NBUK - 1 : k);
    // enforce: k>0 -> x >= XLO+k*XW ; k<NBUK-1 -> x < XLO+(k+1)*XW
#pragma unroll
    for (int it = 0; it < 3; ++it) {
        if (k < NBUK - 1 && x >= XLO + (float)(k + 1) * XW) k++;
        else if (k > 0 && x < XLO + (float)k * XW) k--;
    }
    return k;
}

// ---- 1) bucketize: 8 blocks (sb = set*4+b), 1024 threads, LDS-resident ----
__global__ __launch_bounds__(1024) void bucketize_kernel(
    const float* __restrict__ in1, const float* __restrict__ in2,
    float4* __restrict__ bpts, int* __restrict__ cnt)
{
    __shared__ float4 spts[NPTS];   // 128 KB sorted staging
    __shared__ int h[NBUK];         // counts -> exclusive starts -> cursors
    __shared__ int wsum[16];        // per-wave scan partials

    const int sb = blockIdx.x;
    const float2* __restrict__ src =
        (const float2*)(((sb >= 4) ? in2 : in1) + (size_t)(sb & 3) * NPTS * 2);
    const int t    = threadIdx.x;
    const int lane = t & 63;
    const int w    = t >> 6;

    h[t & (NBUK - 1)] = 0;          // 1024 threads, 1024 bins
    if (sb == 0 && t == 0) *cnt = 0;
    __syncthreads();

    // pass 1: load 8 points/thread into registers, count buckets
    float px[8], py[8];
    int   pk[8];
#pragma unroll
    for (int i = 0; i < 8; ++i) {
        const float2 xy = src[t + (i << 10)];
        px[i] = xy.x; py[i] = xy.y;
        pk[i] = bucket_of(xy.x);
        atomicAdd(&h[pk[i]], 1);
    }
    __syncthreads();

    // exclusive prefix scan of h[1024]: wave shuffle scan + 16 partials
    const int v = h[t];
    int inc = v;
#pragma unroll
    for (int d = 1; d < 64; d <<= 1) {
        const int o = __shfl_up(inc, d, 64);
        if (lane >= d) inc += o;
    }
    if (lane == 63) wsum[w] = inc;
    __syncthreads();
    if (t < 16) {                    // wave 0 scans the 16 wave totals
        int pv = wsum[t];
        int pinc = pv;
#pragma unroll
        for (int d = 1; d < 16; d <<= 1) {
            const int o = __shfl_up(pinc, d, 64);
            if (lane >= d) pinc += o;
        }
        wsum[t] = pinc - pv;         // exclusive wave offset
    }
    __syncthreads();
    h[t] = (inc - v) + wsum[w];      // exclusive start == initial cursor
    __syncthreads();

    // pass 2: place into LDS at sorted positions (cheap LDS scatter).
    // Bucket-internal order is nondeterministic; outputs stay exact via the
    // explicit lex (d, idx) tie-break at query time.
#pragma unroll
    for (int i = 0; i < 8; ++i) {
        const int pos = atomicAdd(&h[pk[i]], 1);
        spts[pos] = make_float4(px[i], py[i], (float)(t + (i << 10)), 0.0f);
    }
    __syncthreads();

    // linear coalesced writeback
#pragma unroll
    for (int i = 0; i < 8; ++i)
        bpts[(size_t)sb * NPTS + t + (i << 10)] = spts[t + (i << 10)];
}

// ---- 2) window scan: 1024 blocks, 64 queries/block, LDS-staged ------------
__global__ __launch_bounds__(256) void window_scan_kernel(
    const float4* __restrict__ bpts, float* __restrict__ out,
    int* __restrict__ cnt, int* __restrict__ queue)
{
    __shared__ float4 win[UNI];          // 9216 B
    __shared__ float pbd[4][64];
    __shared__ float pbz[4][64];

    const int bid = blockIdx.x;
    const int t   = threadIdx.x;
    const int q0slot = bid * 64;         // first qslot of block
    const int db  = q0slot >> 13;        // dir*4 + b  (64 | 8192: no straddle)
    const int dir = db >> 2;
    const int b   = db & 3;
    const int q0  = q0slot & 8191;
    const int qsb = (dir ? 4 : 0) + b;
    const int rsb = (dir ? 0 : 4) + b;

    const float4* __restrict__ Q  = bpts + (size_t)qsb * NPTS;
    const float4* __restrict__ Rf = bpts + (size_t)rsb * NPTS;

    int u0 = q0 - WIN / 2;
    u0 = u0 < 0 ? 0 : (u0 > NPTS - UNI ? NPTS - UNI : u0);

    // stage union [u0, u0+576): coalesced float4 loads
    win[t]       = Rf[u0 + t];
    win[t + 256] = Rf[u0 + 256 + t];
    if (t < UNI - 512) win[t + 512] = Rf[u0 + 512 + t];
    __syncthreads();

    const int s = t >> 6;                // wave id = candidate chunk
    const int L = t & 63;                // lane = query-in-block
    const int qpos = q0 + L;
    const float4 q = Q[qpos];
    const float qx = q.x, qy = q.y;

    int wl = qpos - WIN / 2;
    wl = wl < 0 ? 0 : (wl > NPTS - WIN ? NPTS - WIN : wl);
    const int base = (wl - u0) + (s << 7);   // lane-contiguous -> conflict-free

    // two independent lex-min chains over this wave's 128-candidate chunk
    float bd0 = 1e30f, bd1 = 1e30f, bz0 = 0.0f, bz1 = 0.0f;
    for (int i = 0; i < 128; i += 8) {
#pragma unroll
        for (int u = 0; u < 8; ++u) {
            const float4 r = win[base + i + u];
            const float dx = qx - r.x;
            const float dy = qy - r.y;
            // identical rounding to reference: (dx*dx)+(dy*dy), no FMA
            const float d = __fadd_rn(__fmul_rn(dx, dx), __fmul_rn(dy, dy));
            if (u & 1) {
                const bool c = (d < bd1) || (d == bd1 && r.z < bz1);
                bd1 = c ? d : bd1; bz1 = c ? r.z : bz1;
            } else {
                const bool c = (d < bd0) || (d == bd0 && r.z < bz0);
                bd0 = c ? d : bd0; bz0 = c ? r.z : bz0;
            }
        }
    }
    const bool cm = (bd1 < bd0) || (bd1 == bd0 && bz1 < bz0);
    pbd[s][L] = cm ? bd1 : bd0;
    pbz[s][L] = cm ? bz1 : bz0;
    __syncthreads();

    if (t < 64) {                        // wave 0: combine, certify, write
        float best = pbd[0][L];
        float bif  = pbz[0][L];
#pragma unroll
        for (int k = 1; k < 4; ++k) {
            const float dv = pbd[k][L];
            const float zv = pbz[k][L];
            const bool c = (dv < best) || (dv == best && zv < bif);
            best = c ? dv : best;
            bif  = c ? zv : bif;
        }

        // exact-conservative certification:
        //  left : all p<wl have x <= right_edge(bucket(x[wl-1]))
        //  right: all p>=wl+WIN have x >= left_edge(bucket(x[wl+WIN]))
        //  outside d >= fl(dx^2) >= fl(dxe^2) > best => can't beat or tie
        const int wr = wl + WIN;
        bool okL = (wl == 0), okR = (wr >= NPTS);
        if (!okL) {
            const int kl = bucket_of(Rf[wl - 1].x);
            if (kl < NBUK - 1) {
                const float dxe = qx - (XLO + (float)(kl + 1) * XW);
                okL = (dxe > 0.0f) && (__fmul_rn(dxe, dxe) > best);
            }
        }
        if (!okR) {
            const int kr = bucket_of(Rf[wr].x);
            if (kr > 0) {
                const float dxe = (XLO + (float)kr * XW) - qx;
                okR = (dxe > 0.0f) && (__fmul_rn(dxe, dxe) > best);
            }
        }

        const int qid = (int)q.z;
        const int od  = b * 8192 + qid;
        if (dir == 0) { out[od]         = best; out[65536 + od] = bif; }
        else          { out[32768 + od] = best; out[98304 + od] = bif; }

        if (!(okL && okR)) {
            const int pos = atomicAdd(cnt, 1);
            queue[pos] = q0slot + L;     // db*8192 + qpos
        }
    }
}

// ---- 3) fallback: one wave per failed query (2048 waves) ------------------
__global__ __launch_bounds__(256) void fallback_kernel(
    const float* __restrict__ in1, const float* __restrict__ in2,
    const float4* __restrict__ bpts, const int* __restrict__ cnt,
    const int* __restrict__ queue, float* __restrict__ out)
{
    const int n    = *cnt;
    const int gw   = (blockIdx.x << 2) + (threadIdx.x >> 6);  // global wave id
    const int lane = threadIdx.x & 63;

    for (int item = gw; item < n; item += 2048) {
        const int qslot = queue[item];
        const int qpos  = qslot & 8191;
        const int db    = qslot >> 13;
        const int dir   = db >> 2;
        const int b     = db & 3;
        const int qsb   = (dir ? 4 : 0) + b;
        const float4 q  = bpts[(size_t)qsb * NPTS + qpos];
        const float qx = q.x, qy = q.y;
        // refs in ORIGINAL index order; per-lane j increases -> strict <
        // keeps the first occurrence within a lane
        const float2* __restrict__ P =
            (const float2*)((dir ? in1 : in2) + (size_t)b * NPTS * 2);

        float bd = 1e30f, bz = 0.0f;
#pragma unroll 4
        for (int j = lane; j < NPTS; j += 64) {
            const float2 rp = P[j];
            const float dx = qx - rp.x;
            const float dy = qy - rp.y;
            const float d = __fadd_rn(__fmul_rn(dx, dx), __fmul_rn(dy, dy));
            const bool c = d < bd;
            bd = c ? d : bd;
            bz = c ? (float)j : bz;
        }
        // cross-lane lex (d, idx) reduce
#pragma unroll
        for (int m = 1; m < 64; m <<= 1) {
            const float od = __shfl_xor(bd, m, 64);
            const float oz = __shfl_xor(bz, m, 64);
            const bool c = (od < bd) || (od == bd && oz < bz);
            bd = c ? od : bd;
            bz = c ? oz : bz;
        }
        if (lane == 0) {
            const int qid = (int)q.z;
            const int od  = b * 8192 + qid;
            if (dir == 0) { out[od]         = bd; out[65536 + od] = bz; }
            else          { out[32768 + od] = bd; out[98304 + od] = bz; }
        }
    }
}

extern "C" void kernel_launch(void* const* d_in, const int* in_sizes, int n_in,
                              void* d_out, int out_size, void* d_ws, size_t ws_size,
                              hipStream_t stream) {
    const float* in1 = (const float*)d_in[0];
    const float* in2 = (const float*)d_in[1];
    float* out = (float*)d_out;
    (void)in_sizes; (void)n_in; (void)out_size; (void)ws_size;

    // ws layout: bpts 8*8192*16B = 1 MiB | cnt 4B | queue 65536*4B
    char* w = (char*)d_ws;
    float4* bpts = (float4*)w;
    int* cnt     = (int*)(w + (size_t)8 * NPTS * sizeof(float4));
    int* queue   = cnt + 1;

    bucketize_kernel<<<8, 1024, 0, stream>>>(in1, in2, bpts, cnt);
    window_scan_kernel<<<1024, 256, 0, stream>>>(bpts, out, cnt, queue);
    fallback_kernel<<<512, 256, 0, stream>>>(in1, in2, bpts, cnt, queue, out);
}